// Round 4
// baseline (1065.768 us; speedup 1.0000x reference)
//
#include <hip/hip_runtime.h>
#include <stdint.h>

// Problem constants (match reference)
#define KH 8
#define HD 128
#define GD 64
#define UD 128
#define NPB 128    // nodes per block (8 waves x 16)

// Fragment-major weight image sizes (bf16 elements)
#define WG_K  8192    // per-k Wgh image: 4 t * 4 kb * 64 lanes * 8
#define WU_K 16384    // per-k Wuh image: 8 t * 4 kb * 64 lanes * 8

typedef __attribute__((ext_vector_type(8))) short short8;   // 8 x bf16 (MFMA A/B frag)
typedef __attribute__((ext_vector_type(4))) float f32x4;    // MFMA C/D frag

__device__ __forceinline__ unsigned short f2bf(float x) {
    union { float f; unsigned u; } v; v.f = x;
    return (unsigned short)((v.u + 0x7fffu + ((v.u >> 16) & 1u)) >> 16);  // RNE
}

// ---------------- pre-kernel: bf16-convert weights into FRAGMENT-MAJOR images ----------
// For MFMA 16x16x32 B-operand, lane l=(q<<4)|cc of fragment (t,kb) needs
//   WT[col = t*16+cc][h = kb*32 + q*8 + j], j=0..7   (WT = transposed weight, [out][h])
// Image layout: elem index ((t*4+kb)*64 + l)*8 + j  -> every wave ds_read_b128 is
// uniform-base + lane*16B: conflict-free, pad-free, matches global_load_lds linear dest.
// ws layout (bf16 elements):
//   [0)              : wgImg [k][WG_K]   from Wgh[k][h][g]
//   [KH*WG_K)        : wuImg [k][WU_K]   from Wuh[k][h][u]
//   [.. + KH*WU_K)   : wgvImg [WG_K]     from Wgv[h][g]
__global__ void prep_weights(const float* __restrict__ Wgv,
                             const float* __restrict__ Wgh,
                             const float* __restrict__ Wuh,
                             unsigned short* __restrict__ ws) {
    const int wgN = KH * WG_K;
    const int wuN = KH * WU_K;
    int idx = blockIdx.x * 256 + threadIdx.x;
    if (idx >= wgN + wuN + WG_K) return;
    float val;
    if (idx < wgN) {
        int k = idx >> 13, r = idx & (WG_K - 1);
        int t = r >> 11, kb = (r >> 9) & 3, l = (r >> 3) & 63, j = r & 7;
        int h = kb * 32 + (l >> 4) * 8 + j, g = t * 16 + (l & 15);
        val = Wgh[((size_t)k * HD + h) * GD + g];
    } else if (idx < wgN + wuN) {
        int r0 = idx - wgN;
        int k = r0 >> 14, r = r0 & (WU_K - 1);
        int t = r >> 11, kb = (r >> 9) & 3, l = (r >> 3) & 63, j = r & 7;
        int h = kb * 32 + (l >> 4) * 8 + j, u = t * 16 + (l & 15);
        val = Wuh[((size_t)k * HD + h) * UD + u];
    } else {
        int r = idx - wgN - wuN;
        int t = r >> 11, kb = (r >> 9) & 3, l = (r >> 3) & 63, j = r & 7;
        int h = kb * 32 + (l >> 4) * 8 + j, g = t * 16 + (l & 15);
        val = Wgv[(size_t)h * GD + g];
    }
    ws[idx] = f2bf(val);
}

// async copy of 1KB chunks global->LDS (linear dest == linear source), 8-wave split
__device__ __forceinline__ void cp_lds(const unsigned short* gs, unsigned short* ld,
                                       int nch, int wave, int lane) {
    for (int i = wave; i < nch; i += 8) {
        __builtin_amdgcn_global_load_lds(
            (const __attribute__((address_space(1))) unsigned int*)(gs + i * 512 + lane * 8),
            (__attribute__((address_space(3))) unsigned int*)(ld + i * 512),
            16, 0, 0);
    }
}

// B-fragment read: uniform base + lane*16B, single ds_read_b128, conflict-free
#define BFRAG(base, t, kb) (*(const short8*)&(base)[(((t) * 4 + (kb)) * 64 + lane) * 8])

// Repack one lane's 8 float4 (raw H/vt row data) into the wave's fragment image.
// Loader mapping: lane l owns row rr=l>>2, float4 cols c = (l&3)+4p, p=0..7.
// float4 (rr,c) -> frag kb=c>>3, quad q2=(c>>1)&3, half j=c&1, lane-slot lt=(q2<<4)|rr
// -> 4 bf16 at elem offset kb*512 + lt*8 + j*4 (8B-aligned ds_write_b64).
__device__ __forceinline__ void repack(unsigned short* img, const float4* hr,
                                       int rr, int c0) {
#pragma unroll
    for (int p = 0; p < 8; p++) {
        int c = c0 + 4 * p;
        int kb = c >> 3, q2 = (c >> 1) & 3, j = c & 1;
        int off = kb * 512 + (((q2 << 4) | rr) * 8) + j * 4;
        float4 v = hr[p];
        short4 b;
        b.x = (short)f2bf(v.x); b.y = (short)f2bf(v.y);
        b.z = (short)f2bf(v.z); b.w = (short)f2bf(v.w);
        *(short4*)&img[off] = b;
    }
}

// ---------------- main kernel ----------------------------------------------------------
// Per block: 128 nodes, 8 waves. LDS = 48KB weights (single buffer, block-shared) +
// 8 x 4KB per-wave H fragment images = 80KB exactly -> TWO independent blocks/CU
// (16 waves/CU). H staging is wave-local (no barriers); the only barrier-guarded
// resource is the weight panel: 2 barriers/k around a bare cp_lds, covered by the
// co-resident block. va(k) is pre-read into regs, so compute never touches the image.
__launch_bounds__(512, 4)
__global__ void ghatt_main(const float* __restrict__ vt, const float* __restrict__ H,
                           const unsigned short* __restrict__ ws,
                           float* __restrict__ out, int N) {
    __shared__ __attribute__((aligned(16))) unsigned short lds_w[WG_K + WU_K]; // 49152 B
    __shared__ __attribute__((aligned(16))) unsigned short lds_h[8 * 2048];    // 32768 B

    const int tid  = threadIdx.x;
    const int wave = tid >> 6;
    const int lane = tid & 63;
    const int cc   = lane & 15;   // MFMA col / A-row index (consumer)
    const int q    = lane >> 4;   // quad (consumer)
    const int rr   = lane >> 2;   // loader: row within wave strip (0..15)
    const int c0   = lane & 3;    // loader: float4 col base
    const int nodebase = blockIdx.x * NPB;
    const int hnode = nodebase + wave * 16 + rr;   // loader's global row
    const bool hvalid = hnode < N;

    const unsigned short* wgImg  = ws;
    const unsigned short* wuImg  = ws + (size_t)KH * WG_K;
    const unsigned short* wgvImg = wuImg + (size_t)KH * WU_K;
    unsigned short* img = lds_h + wave * 2048;     // this wave's private image

    const float4 z4 = make_float4(0.f, 0.f, 0.f, 0.f);
    float4 hreg[8];   // raw f32 prefetch: 8 x float4 = this lane's share of the strip

    // ---- prologue --------------------------------------------------------------------
    float4 vr[8];
#pragma unroll
    for (int p = 0; p < 8; p++)
        vr[p] = hvalid ? ((const float4*)vt)[(size_t)hnode * 32 + c0 + 4 * p] : z4;
#pragma unroll
    for (int p = 0; p < 8; p++)
        hreg[p] = hvalid ? ((const float4*)H)[(size_t)hnode * 32 + c0 + 4 * p] : z4;
    cp_lds(wgvImg, lds_w, 16, wave, lane);   // Wgv image into Wg region

    repack(img, vr, rr, c0);                 // vt fragments (wave-local)
    short8 vf[4];
#pragma unroll
    for (int kb = 0; kb < 4; kb++) vf[kb] = *(const short8*)&img[kb * 512 + lane * 8];
    __syncthreads();   // Wgv staged

    // g_key = vt @ Wgv, C-layout: row(node)=4q+r, col(g)=cc+16t — same layout as gq
    f32x4 gkeyv[4];
#pragma unroll
    for (int t = 0; t < 4; t++) {
        f32x4 acc = {0.f, 0.f, 0.f, 0.f};
#pragma unroll
        for (int kb = 0; kb < 4; kb++)
            acc = __builtin_amdgcn_mfma_f32_16x16x32_bf16(vf[kb], BFRAG(lds_w, t, kb), acc, 0, 0, 0);
        gkeyv[t] = acc;
    }
    __syncthreads();   // all waves done reading Wgv region

    cp_lds(wgImg, lds_w,        16, wave, lane);   // weights k=0
    cp_lds(wuImg, lds_w + WG_K, 32, wave, lane);
    repack(img, hreg, rr, c0);                     // H(0) fragments (wave-local)
    short8 va[4];
#pragma unroll
    for (int kb = 0; kb < 4; kb++) va[kb] = *(const short8*)&img[kb * 512 + lane * 8];
    __syncthreads();   // weights(0) staged

    f32x4 Uacc[8];
#pragma unroll
    for (int t = 0; t < 8; t++) { Uacc[t].x = Uacc[t].y = Uacc[t].z = Uacc[t].w = 0.f; }
    float den[4] = {0.f, 0.f, 0.f, 0.f};

    // ---- k loop ------------------------------------------------------------------------
    for (int k = 0; k < KH; k++) {
        // issue next H prefetch first: HBM latency hides under the whole compute phase
        if (k < KH - 1) {
#pragma unroll
            for (int p = 0; p < 8; p++)
                hreg[p] = hvalid
                    ? ((const float4*)H)[((size_t)(k + 1) * N + hnode) * 32 + c0 + 4 * p] : z4;
        }

        // g_query = H @ Wgh[k]  (C-layout, matches gkeyv)
        f32x4 gqv[4];
#pragma unroll
        for (int t = 0; t < 4; t++) {
            f32x4 acc = {0.f, 0.f, 0.f, 0.f};
#pragma unroll
            for (int kb = 0; kb < 4; kb++)
                acc = __builtin_amdgcn_mfma_f32_16x16x32_bf16(va[kb], BFRAG(lds_w, t, kb), acc, 0, 0, 0);
            gqv[t] = acc;
        }

        // score: per-row dot over g, reduced across the 16 column-lanes of each quad
        float part[4];
#pragma unroll
        for (int r = 0; r < 4; r++)
            part[r] = gqv[0][r] * gkeyv[0][r] + gqv[1][r] * gkeyv[1][r]
                    + gqv[2][r] * gkeyv[2][r] + gqv[3][r] * gkeyv[3][r];
#pragma unroll
        for (int m2 = 1; m2 < 16; m2 <<= 1) {
#pragma unroll
            for (int r = 0; r < 4; r++) part[r] += __shfl_xor(part[r], m2);
        }
        float gg[4];
#pragma unroll
        for (int r = 0; r < 4; r++) {
            float x = part[r];
            x = (x >= 0.f) ? x : 0.01f * x;      // LeakyReLU(0.01)
            gg[r] = __expf(x * 0.125f);          // / sqrt(64)
            den[r] += gg[r];
        }

        // U += g * (H @ Wuh[k]), all 128 u-columns
#pragma unroll
        for (int t = 0; t < 8; t++) {
            f32x4 acc = {0.f, 0.f, 0.f, 0.f};
#pragma unroll
            for (int kb = 0; kb < 4; kb++)
                acc = __builtin_amdgcn_mfma_f32_16x16x32_bf16(va[kb], BFRAG(lds_w + WG_K, t, kb), acc, 0, 0, 0);
#pragma unroll
            for (int r = 0; r < 4; r++) Uacc[t][r] += gg[r] * acc[r];
        }

        __syncthreads();   // all waves done reading weight panel k
        if (k < KH - 1) {
            cp_lds(wgImg + (size_t)(k + 1) * WG_K, lds_w,        16, wave, lane);
            cp_lds(wuImg + (size_t)(k + 1) * WU_K, lds_w + WG_K, 32, wave, lane);
            // wave-local H(k+1) repack + va pre-read overlap the cp_lds L2 latency
            repack(img, hreg, rr, c0);
#pragma unroll
            for (int kb = 0; kb < 4; kb++) va[kb] = *(const short8*)&img[kb * 512 + lane * 8];
        }
        __syncthreads();   // weight panel k+1 staged (vmcnt/lgkm drain)
    }

    // ---- epilogue: normalize, lrelu, store ---------------------------------------------
    float inv[4];
#pragma unroll
    for (int r = 0; r < 4; r++) inv[r] = 1.f / den[r];
#pragma unroll
    for (int t = 0; t < 8; t++) {
#pragma unroll
        for (int r = 0; r < 4; r++) {
            float u = Uacc[t][r] * inv[r];
            u = (u >= 0.f) ? u : 0.01f * u;
            int node = nodebase + wave * 16 + 4 * q + r;
            if (node < N) out[(size_t)node * UD + t * 16 + cc] = u;
        }
    }
}

extern "C" void kernel_launch(void* const* d_in, const int* in_sizes, int n_in,
                              void* d_out, int out_size, void* d_ws, size_t ws_size,
                              hipStream_t stream) {
    const float* vt  = (const float*)d_in[0];
    const float* H   = (const float*)d_in[1];
    const float* Wgv = (const float*)d_in[2];
    const float* Wgh = (const float*)d_in[3];
    const float* Wuh = (const float*)d_in[4];
    float* out = (float*)d_out;
    unsigned short* wsw = (unsigned short*)d_ws;

    const int N = in_sizes[0] / HD;   // vt is [N,128]

    // weight prep: KH*(WG_K+WU_K) + WG_K = 204800 bf16 elements = 400 KB of d_ws
    const int prepTot = KH * (WG_K + WU_K) + WG_K;
    hipLaunchKernelGGL(prep_weights, dim3((prepTot + 255) / 256), dim3(256), 0, stream,
                       Wgv, Wgh, Wuh, wsw);

    hipLaunchKernelGGL(ghatt_main, dim3((N + NPB - 1) / NPB), dim3(512), 0, stream,
                       vt, H, wsw, out, N);
}